// Round 6
// baseline (698.361 us; speedup 1.0000x reference)
//
#include <hip/hip_runtime.h>
#include <math.h>
#include <limits.h>
#include <stdint.h>

#define QMAXF 127.0f
#define BN_EPS 1e-5f
#define NCOPIES 64

typedef int v4i __attribute__((ext_vector_type(4)));

// ---------- helpers ----------
__device__ __forceinline__ int f2ord(float f){
    int i = __float_as_int(f);
    return i ^ ((i >> 31) & 0x7fffffff);
}
__device__ __forceinline__ float ord2f(int i){
    return __int_as_float(i ^ ((i >> 31) & 0x7fffffff));
}
// fake-quant forward: clip(round(x/s))*s  (round = half-to-even, matches jnp.round)
__device__ __forceinline__ float fq_apply(float x, float s){
    float q = rintf(x / s);
    q = fminf(fmaxf(q, -QMAXF), QMAXF);
    return q * s;
}
// return clipped integer level as float
__device__ __forceinline__ float quant_k(float x, float s){
    float q = rintf(x / s);
    return fminf(fmaxf(q, -QMAXF), QMAXF);
}

// ---------- K0: init stat buffers ----------
__global__ void k_init_stats(int* s1, int* s2, int* sf, int* so){
    int t = blockIdx.x*blockDim.x + threadIdx.x;
    if (t < 2048){ int j = t & 31; s1[t] = (j < 16) ? INT_MAX : INT_MIN; }
    else if (t < 6144){ int u = t - 2048; int j = u & 63; s2[u] = (j < 32) ? INT_MAX : INT_MIN; }
    else if (t < 6272){ int u = t - 6144; sf[u] = ((u & 1) == 0) ? INT_MAX : INT_MIN; }
    else if (t < 6400){ int u = t - 6272; so[u] = ((u & 1) == 0) ? INT_MAX : INT_MIN; }
}

// ---------- K1a: per-tensor weight scales ----------
__global__ __launch_bounds__(1024) void k_wscales(
    const float* __restrict__ w1, const float* __restrict__ w2,
    const float* __restrict__ fw1, const float* __restrict__ fw2,
    float* __restrict__ wscales)
{
    __shared__ float red[1024];
    int t = threadIdx.x, which = blockIdx.x;
    const float* src; int n;
    if (which == 0){ src = w1;  n = 144; }
    else if (which == 1){ src = w2;  n = 4608; }
    else if (which == 2){ src = fw1; n = 200704; }
    else { src = fw2; n = 1280; }
    float mval = 0.f;
    for (int i = t; i < n; i += 1024) mval = fmaxf(mval, fabsf(src[i]));
    red[t] = mval; __syncthreads();
    for (int off = 512; off; off >>= 1){
        if (t < off) red[t] = fmaxf(red[t], red[t+off]);
        __syncthreads();
    }
    if (t == 0) wscales[which] = fmaxf(red[0] / QMAXF, 1e-8f);
}

// ---------- K1b: pack/quantize weights ----------
__global__ __launch_bounds__(256) void k_pack_weights(
    const float* __restrict__ w1, const float* __restrict__ w2,
    const float* __restrict__ fw1, const float* __restrict__ fw2,
    const float* __restrict__ wscales,
    float* __restrict__ qw1, int8_t* __restrict__ wpk2,
    int8_t* __restrict__ bpk1, float* __restrict__ qfw2)
{
    int blk = blockIdx.x, t = threadIdx.x;
    if (blk < 784){
        float s = wscales[2];
        int i = blk*256 + t;                      // 200704 exact
        int o = i / 1568, k = i - o*1568;
        int c = k / 49, r = k - c*49;
        int kp = r*32 + c;
        int kchunk = kp >> 6, rem = kp & 63, hi = rem >> 4, j = rem & 15;
        int code = (int)quant_k(fw1[i], s);
        bpk1[(o>>4)*25600 + (kchunk*4 + hi)*256 + (o&15)*16 + j] = (int8_t)code;
    } else if (blk == 784){
        float s0 = wscales[0], s3 = wscales[3];
        for (int i = t; i < 144; i += 256) qw1[i] = fq_apply(w1[i], s0);
        for (int i = t; i < 1280; i += 256) qfw2[i] = fq_apply(fw2[i], s3);
        for (int i = t; i < 4096; i += 256){
            int o = i >> 5, rem = (i & 31) + 32;  // kp 1568..1599 -> chunk24
            int hi = rem >> 4, j = rem & 15;
            bpk1[(o>>4)*25600 + (24*4 + hi)*256 + (o&15)*16 + j] = 0;
        }
    } else {
        float s1 = wscales[1];
        for (int i = t; i < 6144; i += 256) wpk2[i] = 0;
        __syncthreads();
        for (int i = t; i < 4608; i += 256){
            int co = i / 144, rr = i - co*144, ci = rr / 9, pix = rr - ci*9;
            wpk2[(co >> 4)*3072 + pix*256 + (co & 15)*16 + ci] = (int8_t)(int)quant_k(w2[i], s1);
        }
    }
}

// ---------- K2: conv1 + per-channel min/max (channel-split: 4 ch/block) ----------
// block = (pos_block, cg); thread = (b, y, q): 4 consecutive x outputs.
// asm "+v" pins: window values become opaque VGPRs -> loads cannot be rematerialized.
__global__ __launch_bounds__(256) void k_conv1_stats(
    const float* __restrict__ x, const float* __restrict__ qw1, const float* __restrict__ b1,
    int* __restrict__ stats1 /*[64][32]*/)
{
    __shared__ int smin[4], smax[4];
    int t = threadIdx.x;
    int cg = blockIdx.x & 3;
    int pb = blockIdx.x >> 2;           // 0..6271
    if (t < 4){ smin[t] = INT_MAX; smax[t] = INT_MIN; }
    float sw[36], sb[4];
    #pragma unroll
    for (int i = 0; i < 36; i++) sw[i] = qw1[cg*36 + i];   // wave-uniform -> SGPR
    #pragma unroll
    for (int c = 0; c < 4; c++) sb[c] = b1[cg*4 + c];
    __syncthreads();
    float mn[4], mx[4];
    #pragma unroll
    for (int c = 0; c < 4; c++){ mn[c] = INFINITY; mx[c] = -INFINITY; }
    int tid = pb*256 + t;               // 1,605,632 = 8192*28*7 exact
    int q = tid % 7;
    int rowid = tid / 7;
    int y = rowid % 28;
    int b = rowid / 28;
    const float* xb = x + (size_t)b*784;
    int x0 = 4*q;
    float r[3][6];
    #pragma unroll
    for (int j = 0; j < 3; j++){
        int yy = y - 1 + j;
        if (yy < 0 || yy > 27){
            #pragma unroll
            for (int i2 = 0; i2 < 6; i2++) r[j][i2] = 0.f;
        } else {
            const float* rp = xb + yy*28;
            float4 f = *(const float4*)(rp + x0);
            r[j][1] = f.x; r[j][2] = f.y; r[j][3] = f.z; r[j][4] = f.w;
            r[j][0] = (q > 0) ? rp[x0-1] : 0.f;
            r[j][5] = (q < 6) ? rp[x0+4] : 0.f;
        }
    }
    #pragma unroll
    for (int j = 0; j < 3; j++)
        #pragma unroll
        for (int i2 = 0; i2 < 6; i2++)
            asm volatile("" : "+v"(r[j][i2]));   // pin in VGPR, forbid remat
    #pragma unroll
    for (int px = 0; px < 4; px++){
        #pragma unroll
        for (int c = 0; c < 4; c++){
            float a = sb[c];
            #pragma unroll
            for (int ky = 0; ky < 3; ky++)
                #pragma unroll
                for (int kx = 0; kx < 3; kx++)
                    a = fmaf(sw[c*9 + ky*3 + kx], r[ky][px + kx], a);
            mn[c] = fminf(mn[c], a);
            mx[c] = fmaxf(mx[c], a);
        }
    }
    #pragma unroll
    for (int c = 0; c < 4; c++){
        atomicMin(&smin[c], f2ord(mn[c]));
        atomicMax(&smax[c], f2ord(mx[c]));
    }
    __syncthreads();
    if (t < 4){
        int* base = stats1 + (blockIdx.x & (NCOPIES-1))*32;
        atomicMin(&base[cg*4 + t],      smin[t]);
        atomicMax(&base[16 + cg*4 + t], smax[t]);
    }
}

// ---------- scales for block1 ----------
__global__ void k_scales_block(int C, const int* __restrict__ stats,
                               const float* __restrict__ g, const float* __restrict__ be,
                               const float* __restrict__ m, const float* __restrict__ v,
                               float* __restrict__ s_out, float* __restrict__ bnA, float* __restrict__ bnB)
{
    __shared__ float cmn[32], cmx[32];
    int t = threadIdx.x;
    if (t < 2*C){
        bool ismax = t >= C; int c = ismax ? t - C : t;
        int acc = ismax ? INT_MIN : INT_MAX;
        for (int i = 0; i < NCOPIES; i++){
            int u = stats[i*2*C + t];
            acc = ismax ? max(acc, u) : min(acc, u);
        }
        if (ismax) cmx[c] = ord2f(acc); else cmn[c] = ord2f(acc);
    }
    __syncthreads();
    if (t == 0){
        float am = 0.f;
        for (int c = 0; c < C; c++) am = fmaxf(am, fmaxf(fabsf(cmn[c]), fabsf(cmx[c])));
        float sA_ = fmaxf(am / QMAXF, 1e-8f);
        float rmax = 0.f;
        float q1x[32], q1n[32];
        for (int c = 0; c < C; c++){
            q1x[c] = fmaxf(fq_apply(cmx[c], sA_), 0.f);
            q1n[c] = fmaxf(fq_apply(cmn[c], sA_), 0.f);
            rmax = fmaxf(rmax, q1x[c]);
        }
        float sB_ = fmaxf(rmax / QMAXF, 1e-8f);
        float am3 = 0.f;
        for (int c = 0; c < C; c++){
            float inv = g[c] / sqrtf(v[c] + BN_EPS);
            float dd  = be[c] - m[c]*inv;
            bnA[c] = inv; bnB[c] = dd;
            float ha = fmaf(fq_apply(q1x[c], sB_), inv, dd);
            float hb = fmaf(fq_apply(q1n[c], sB_), inv, dd);
            am3 = fmaxf(am3, fmaxf(fabsf(ha), fabsf(hb)));
        }
        float sC_ = fmaxf(am3 / QMAXF, 1e-8f);
        s_out[0] = sA_; s_out[1] = sB_; s_out[2] = sC_;
    }
}

// ---------- K4: fused block1, channel-split (4 ch/block), pool-before-chain (exact) ----------
__global__ __launch_bounds__(256) void k_block1(
    const float* __restrict__ x, const float* __restrict__ qw1, const float* __restrict__ b1,
    const float* __restrict__ scales, const float* __restrict__ bnA, const float* __restrict__ bnB,
    int8_t* __restrict__ h1q)
{
    int t = threadIdx.x;
    int cg = blockIdx.x & 3;
    int pb = blockIdx.x >> 2;            // 0..3135
    float sw[36], sb[4], sA[4], sB[4];
    #pragma unroll
    for (int i = 0; i < 36; i++) sw[i] = qw1[cg*36 + i];
    #pragma unroll
    for (int c = 0; c < 4; c++){
        sb[c] = b1[cg*4 + c]; sA[c] = bnA[cg*4 + c]; sB[c] = bnB[cg*4 + c];
    }
    float s1 = scales[0], s2 = scales[1], s3 = scales[2];
    int tid = pb*256 + t;                // 802,816 = 8192*14*7 exact
    int q = tid % 7;
    int rest = tid / 7;
    int py = rest % 14;
    int b = rest / 14;
    const float* xb = x + (size_t)b*784;
    int x0 = 4*q;
    float r[4][6];
    #pragma unroll
    for (int j = 0; j < 4; j++){
        int yy = 2*py - 1 + j;
        if (yy < 0 || yy > 27){
            #pragma unroll
            for (int i2 = 0; i2 < 6; i2++) r[j][i2] = 0.f;
        } else {
            const float* rp = xb + yy*28;
            float4 f = *(const float4*)(rp + x0);
            r[j][1] = f.x; r[j][2] = f.y; r[j][3] = f.z; r[j][4] = f.w;
            r[j][0] = (q > 0) ? rp[x0-1] : 0.f;
            r[j][5] = (q < 6) ? rp[x0+4] : 0.f;
        }
    }
    #pragma unroll
    for (int j = 0; j < 4; j++)
        #pragma unroll
        for (int i2 = 0; i2 < 6; i2++)
            asm volatile("" : "+v"(r[j][i2]));   // pin in VGPR, forbid remat
    int p = b*196 + py*14 + 2*q;
    #pragma unroll
    for (int po = 0; po < 2; po++){
        int o4[4];
        #pragma unroll
        for (int c = 0; c < 4; c++){
            float pool = -INFINITY;
            #pragma unroll
            for (int oy = 0; oy < 2; oy++){
                #pragma unroll
                for (int ox = 0; ox < 2; ox++){
                    float a = sb[c];
                    #pragma unroll
                    for (int ky = 0; ky < 3; ky++)
                        #pragma unroll
                        for (int kx = 0; kx < 3; kx++)
                            a = fmaf(sw[c*9 + ky*3 + kx], r[oy+ky][2*po + ox + kx], a);
                    pool = fmaxf(pool, a);
                }
            }
            float h = fq_apply(pool, s1);
            h = fmaxf(h, 0.f);
            h = fq_apply(h, s2);
            h = fmaf(h, sA[c], sB[c]);
            o4[c] = (int)quant_k(h, s3);
        }
        int pk = (o4[0]&255) | ((o4[1]&255)<<8) | ((o4[2]&255)<<16) | ((o4[3]&255)<<24);
        ((int*)h1q)[(p + po)*4 + cg] = pk;
    }
}

// ---------- conv2 MFMA tile ----------
__device__ __forceinline__ void conv2_tile_mfma(
    const int8_t* __restrict__ h1q, const v4i* __restrict__ bv,
    int tile, int l, v4i& acc0, v4i& acc1)
{
    int grow = tile*16 + (l & 15);
    int cell_g = grow >> 2;
    int b = cell_g / 49, cell = cell_g - b*49;
    int sub = grow & 3;
    int qy = cell / 7, qx = cell - qy*7;
    int y = 2*qy + (sub >> 1);
    int x = 2*qx + (sub & 1);
    size_t base = (size_t)b * 196;
    int hi = l >> 4;
    acc0 = (v4i){0,0,0,0};
    acc1 = (v4i){0,0,0,0};
    #pragma unroll
    for (int s = 0; s < 3; s++){
        int tap = 4*s + hi;
        v4i av = {0,0,0,0};
        if (tap < 9){
            int ky = tap / 3, kx = tap - ky*3;
            int yy = y + ky - 1, xc = x + kx - 1;
            if (yy >= 0 && yy < 14 && xc >= 0 && xc < 14)
                av = *(const v4i*)(h1q + (base + yy*14 + xc)*16);
        }
        acc0 = __builtin_amdgcn_mfma_i32_16x16x64_i8(av, bv[s],     acc0, 0, 0, 0);
        acc1 = __builtin_amdgcn_mfma_i32_16x16x64_i8(av, bv[3 + s], acc1, 0, 0, 0);
    }
}

// ---------- K6: conv2 int8 MFMA + per-channel code min/max ----------
__global__ __launch_bounds__(256) void k_conv2s_mfma(
    const int8_t* __restrict__ h1q, const int8_t* __restrict__ wpk2,
    int* __restrict__ stats2)
{
    __shared__ int smn[32], smx[32];
    int t = threadIdx.x, l = t & 63, wid = t >> 6;
    if (t < 32){ smn[t] = INT_MAX; smx[t] = INT_MIN; }
    __syncthreads();
    v4i bv[6];
    #pragma unroll
    for (int nt = 0; nt < 2; nt++)
        #pragma unroll
        for (int s = 0; s < 3; s++)
            bv[nt*3+s] = *(const v4i*)(wpk2 + nt*3072 + (4*s + (l>>4))*256 + (l&15)*16);
    int mn0 = INT_MAX, mx0 = INT_MIN, mn1 = INT_MAX, mx1 = INT_MIN;
    #pragma unroll 1
    for (int it = 0; it < 16; it++){            // 1568 blocks * 16 = 25088 tiles
        int tb = blockIdx.x + it*1568;
        v4i acc0, acc1;
        conv2_tile_mfma(h1q, bv, tb*4 + wid, l, acc0, acc1);
        #pragma unroll
        for (int r = 0; r < 4; r++){
            mn0 = min(mn0, acc0[r]); mx0 = max(mx0, acc0[r]);
            mn1 = min(mn1, acc1[r]); mx1 = max(mx1, acc1[r]);
        }
    }
    mn0 = min(mn0, __shfl_xor(mn0, 16)); mn0 = min(mn0, __shfl_xor(mn0, 32));
    mx0 = max(mx0, __shfl_xor(mx0, 16)); mx0 = max(mx0, __shfl_xor(mx0, 32));
    mn1 = min(mn1, __shfl_xor(mn1, 16)); mn1 = min(mn1, __shfl_xor(mn1, 32));
    mx1 = max(mx1, __shfl_xor(mx1, 16)); mx1 = max(mx1, __shfl_xor(mx1, 32));
    if (l < 16){
        atomicMin(&smn[l], mn0);      atomicMax(&smx[l], mx0);
        atomicMin(&smn[16 + l], mn1); atomicMax(&smx[16 + l], mx1);
    }
    __syncthreads();
    if (t < 32){
        int* base = stats2 + (blockIdx.x & (NCOPIES-1))*64;
        atomicMin(&base[t],      smn[t]);
        atomicMax(&base[t + 32], smx[t]);
    }
}

// ---------- scales for block2 from int code stats ----------
__global__ void k_scales2(const int* __restrict__ stats,
                          const float* __restrict__ g, const float* __restrict__ be,
                          const float* __restrict__ m, const float* __restrict__ v,
                          const float* __restrict__ b2,
                          const float* __restrict__ scales, const float* __restrict__ wscales,
                          float* __restrict__ s_out, float* __restrict__ bnA, float* __restrict__ bnB)
{
    __shared__ float cmn[32], cmx[32];
    int t = threadIdx.x;
    float S = scales[2] * wscales[1];
    if (t < 64){
        bool ismax = t >= 32; int c = t & 31;
        int acc = ismax ? INT_MIN : INT_MAX;
        for (int i = 0; i < NCOPIES; i++){
            int u = stats[i*64 + t];
            acc = ismax ? max(acc, u) : min(acc, u);
        }
        float val = fmaf(S, (float)acc, b2[c]);
        if (ismax) cmx[c] = val; else cmn[c] = val;
    }
    __syncthreads();
    if (t == 0){
        float am = 0.f;
        for (int c = 0; c < 32; c++) am = fmaxf(am, fmaxf(fabsf(cmn[c]), fabsf(cmx[c])));
        float sA_ = fmaxf(am / QMAXF, 1e-8f);
        float rmax = 0.f;
        float q1x[32], q1n[32];
        for (int c = 0; c < 32; c++){
            q1x[c] = fmaxf(fq_apply(cmx[c], sA_), 0.f);
            q1n[c] = fmaxf(fq_apply(cmn[c], sA_), 0.f);
            rmax = fmaxf(rmax, q1x[c]);
        }
        float sB_ = fmaxf(rmax / QMAXF, 1e-8f);
        float am3 = 0.f;
        for (int c = 0; c < 32; c++){
            float inv = g[c] / sqrtf(v[c] + BN_EPS);
            float dd  = be[c] - m[c]*inv;
            bnA[c] = inv; bnB[c] = dd;
            float ha = fmaf(fq_apply(q1x[c], sB_), inv, dd);
            float hb = fmaf(fq_apply(q1n[c], sB_), inv, dd);
            am3 = fmaxf(am3, fmaxf(fabsf(ha), fabsf(hb)));
        }
        float sC_ = fmaxf(am3 / QMAXF, 1e-8f);
        s_out[0] = sA_; s_out[1] = sB_; s_out[2] = sC_;
    }
}

// ---------- K8: conv2 MFMA -> pool -> chain -> h2q codes (4 tiles/wave) ----------
__global__ __launch_bounds__(256) void k_block2_mfma(
    const int8_t* __restrict__ h1q, const int8_t* __restrict__ wpk2,
    const float* __restrict__ b2, const float* __restrict__ scales,
    const float* __restrict__ wscales,
    const float* __restrict__ bnA, const float* __restrict__ bnB,
    int8_t* __restrict__ h2q)
{
    __shared__ float sb[32], sA[32], sB[32];
    __shared__ int pbufi[512];
    char* pbuf = (char*)pbufi;
    int t = threadIdx.x, l = t & 63, wid = t >> 6;
    if (t < 32){ sb[t] = b2[t]; sA[t] = bnA[t]; sB[t] = bnB[t]; }
    __syncthreads();
    float S = scales[2] * wscales[1];
    float s4 = scales[3], s5 = scales[4], s6 = scales[5];
    v4i bv[6];
    #pragma unroll
    for (int nt = 0; nt < 2; nt++)
        #pragma unroll
        for (int s = 0; s < 3; s++)
            bv[nt*3+s] = *(const v4i*)(wpk2 + nt*3072 + (4*s + (l>>4))*256 + (l&15)*16);
    #pragma unroll 1
    for (int it = 0; it < 4; it++){
        int tile = blockIdx.x*16 + wid*4 + it;   // grid 6272: tiles 0..100351
        v4i acc0, acc1;
        conv2_tile_mfma(h1q, bv, tile, l, acc0, acc1);
        int cell_local = wid*16 + it*4 + (l >> 4);
        #pragma unroll
        for (int nt = 0; nt < 2; nt++){
            v4i a = nt ? acc1 : acc0;
            int pool = max(max(a[0], a[1]), max(a[2], a[3]));
            int co = nt*16 + (l & 15);
            float conv = fmaf(S, (float)pool, sb[co]);
            float h = fq_apply(conv, s4);
            h = fmaxf(h, 0.f);
            h = fq_apply(h, s5);
            h = fmaf(h, sA[co], sB[co]);
            pbuf[cell_local*32 + co] = (char)(int)quant_k(h, s6);
        }
    }
    __syncthreads();
    #pragma unroll
    for (int i = t; i < 512; i += 256)
        ((int*)h2q)[blockIdx.x*512 + i] = pbufi[i];
}

// ---------- K9: fc1 int8 MFMA: M=8192, N=128, K=1600 (padded) ----------
__global__ __launch_bounds__(256) void k_fc1(
    const int8_t* __restrict__ h2q, const int8_t* __restrict__ bpk1,
    const float* __restrict__ fb1, const float* __restrict__ scales,
    const float* __restrict__ wscales,
    float* __restrict__ fc1o, int* __restrict__ statsFc)
{
    __shared__ int smn, smx;
    int t = threadIdx.x, l = t & 63, wid = t >> 6;
    if (t == 0){ smn = INT_MAX; smx = INT_MIN; }
    __syncthreads();
    int wave_id = blockIdx.x*4 + wid;     // 1024 waves
    int mtile = wave_id >> 1;             // 0..511
    int half = wave_id & 1;
    int hi = l >> 4, lo = l & 15;
    const int8_t* arow = h2q + (size_t)(mtile*16 + lo)*1568;
    v4i acc[4];
    #pragma unroll
    for (int g = 0; g < 4; g++) acc[g] = (v4i){0,0,0,0};
    #pragma unroll 1
    for (int kc = 0; kc < 25; kc++){
        int koff = kc*64 + hi*16;
        v4i av = (v4i){0,0,0,0};
        if (koff < 1568) av = *(const v4i*)(arow + koff);
        #pragma unroll
        for (int g = 0; g < 4; g++){
            v4i bvv = *(const v4i*)(bpk1 + (half*4 + g)*25600 + (kc*4 + hi)*256 + lo*16);
            acc[g] = __builtin_amdgcn_mfma_i32_16x16x64_i8(av, bvv, acc[g], 0, 0, 0);
        }
    }
    float Sfc = scales[5] * wscales[2];
    float lmn = INFINITY, lmx = -INFINITY;
    #pragma unroll
    for (int g = 0; g < 4; g++){
        int o = (half*4 + g)*16 + lo;
        float bias = fb1[o];
        #pragma unroll
        for (int r = 0; r < 4; r++){
            int m = mtile*16 + hi*4 + r;
            float val = fmaf(Sfc, (float)acc[g][r], bias);
            fc1o[(size_t)m*128 + o] = val;
            lmn = fminf(lmn, val); lmx = fmaxf(lmx, val);
        }
    }
    #pragma unroll
    for (int d = 1; d < 64; d <<= 1){
        lmn = fminf(lmn, __shfl_xor(lmn, d));
        lmx = fmaxf(lmx, __shfl_xor(lmx, d));
    }
    if (l == 0){
        atomicMin(&smn, f2ord(lmn));
        atomicMax(&smx, f2ord(lmx));
    }
    __syncthreads();
    if (t == 0){
        int* base = statsFc + (blockIdx.x & (NCOPIES-1))*2;
        atomicMin(&base[0], smn); atomicMax(&base[1], smx);
    }
}

// ---------- K12: fc2 with inline h3 quantization (s7/s8 derived in prologue) ----------
__global__ __launch_bounds__(256) void k_fc2(
    const float* __restrict__ fc1o, const float* __restrict__ qfw2, const float* __restrict__ fb2,
    const int* __restrict__ statsFc, float* __restrict__ out, int* __restrict__ statsOut)
{
    __shared__ float sw[1280], sb2[10];
    __shared__ float s7s, s8s;
    __shared__ int smn, smx;
    int t = threadIdx.x;
    for (int i = t; i < 1280; i += 256) sw[i] = qfw2[i];
    if (t < 10) sb2[t] = fb2[t];
    if (t == 0){
        smn = INT_MAX; smx = INT_MIN;
        int mni = INT_MAX, mxi = INT_MIN;
        for (int i = 0; i < NCOPIES; i++){ mni = min(mni, statsFc[i*2]); mxi = max(mxi, statsFc[i*2+1]); }
        float mn = ord2f(mni), mx = ord2f(mxi);
        float am = fmaxf(fabsf(mn), fabsf(mx));
        float s7 = fmaxf(am / QMAXF, 1e-8f);
        float rmx = fmaxf(fq_apply(mx, s7), 0.f);
        s7s = s7; s8s = fmaxf(rmx / QMAXF, 1e-8f);
    }
    __syncthreads();
    float s7 = s7s, s8 = s8s;
    int b = blockIdx.x*256 + t;   // 8192 exact (32 blocks)
    float acc[10];
    #pragma unroll
    for (int j = 0; j < 10; j++) acc[j] = sb2[j];
    const float* fp = fc1o + (size_t)b*128;
    for (int k = 0; k < 128; k += 4){
        float4 f = *(const float4*)(fp + k);
        float v0 = s8 * quant_k(fmaxf(fq_apply(f.x, s7), 0.f), s8);
        float v1 = s8 * quant_k(fmaxf(fq_apply(f.y, s7), 0.f), s8);
        float v2 = s8 * quant_k(fmaxf(fq_apply(f.z, s7), 0.f), s8);
        float v3 = s8 * quant_k(fmaxf(fq_apply(f.w, s7), 0.f), s8);
        #pragma unroll
        for (int j = 0; j < 10; j++){
            float a = acc[j];
            a = fmaf(v0, sw[j*128 + k],     a);
            a = fmaf(v1, sw[j*128 + k + 1], a);
            a = fmaf(v2, sw[j*128 + k + 2], a);
            a = fmaf(v3, sw[j*128 + k + 3], a);
            acc[j] = a;
        }
    }
    float lmn = INFINITY, lmx = -INFINITY;
    #pragma unroll
    for (int j = 0; j < 10; j++){
        out[(size_t)b*10 + j] = acc[j];
        lmn = fminf(lmn, acc[j]); lmx = fmaxf(lmx, acc[j]);
    }
    atomicMin(&smn, f2ord(lmn)); atomicMax(&smx, f2ord(lmx));
    __syncthreads();
    if (t == 0){
        int* base = statsOut + (blockIdx.x & (NCOPIES-1))*2;
        atomicMin(&base[0], smn); atomicMax(&base[1], smx);
    }
}

// ---------- K14: final fake-quant of d_out (s9 derived in prologue) ----------
__global__ void k_quant_out(float* __restrict__ out, const int* __restrict__ statsOut, int n){
    __shared__ float s9s;
    if (threadIdx.x == 0){
        int mni = INT_MAX, mxi = INT_MIN;
        for (int i = 0; i < NCOPIES; i++){ mni = min(mni, statsOut[i*2]); mxi = max(mxi, statsOut[i*2+1]); }
        float am = fmaxf(fabsf(ord2f(mni)), fabsf(ord2f(mxi)));
        s9s = fmaxf(am / QMAXF, 1e-8f);
    }
    __syncthreads();
    int i = blockIdx.x*256 + threadIdx.x;
    if (i < n) out[i] = fq_apply(out[i], s9s);
}

// =================== host ===================
extern "C" void kernel_launch(void* const* d_in, const int* in_sizes, int n_in,
                              void* d_out, int out_size, void* d_ws, size_t ws_size,
                              hipStream_t stream)
{
    const float* x   = (const float*)d_in[0];
    const float* w1  = (const float*)d_in[1];
    const float* b1  = (const float*)d_in[2];
    const float* g1  = (const float*)d_in[3];
    const float* be1 = (const float*)d_in[4];
    const float* m1  = (const float*)d_in[5];
    const float* v1  = (const float*)d_in[6];
    const float* w2  = (const float*)d_in[7];
    const float* b2  = (const float*)d_in[8];
    const float* g2  = (const float*)d_in[9];
    const float* be2 = (const float*)d_in[10];
    const float* m2  = (const float*)d_in[11];
    const float* v2  = (const float*)d_in[12];
    const float* fw1 = (const float*)d_in[13];
    const float* fb1 = (const float*)d_in[14];
    const float* fw2 = (const float*)d_in[15];
    const float* fb2 = (const float*)d_in[16];
    float* out = (float*)d_out;

    char* ws = (char*)d_ws;
    size_t off = 0;
    auto alloc = [&](size_t bytes)->char*{
        char* p = ws + off;
        off = (off + bytes + 255) & ~(size_t)255;
        return p;
    };
    float* qw1    = (float*)alloc(144*4);
    int8_t* wpk2  = (int8_t*)alloc(6144);
    int8_t* bpk1  = (int8_t*)alloc(204800);
    float* qfw2   = (float*)alloc(1280*4);
    float* scales = (float*)alloc(16*4);
    float* wscales= (float*)alloc(4*4);
    float* bn1A   = (float*)alloc(16*4);
    float* bn1B   = (float*)alloc(16*4);
    float* bn2A   = (float*)alloc(32*4);
    float* bn2B   = (float*)alloc(32*4);
    int* stats1   = (int*)alloc(64*32*4);
    int* stats2   = (int*)alloc(64*64*4);
    int* statsFc  = (int*)alloc(64*2*4);
    int* statsOut = (int*)alloc(64*2*4);
    int8_t* h1q   = (int8_t*)alloc((size_t)8192*196*16);
    int8_t* h2q   = (int8_t*)alloc((size_t)8192*49*32);
    float* fc1o   = (float*)alloc((size_t)8192*128*4);
    (void)ws_size;

    k_init_stats<<<25, 256, 0, stream>>>(stats1, stats2, statsFc, statsOut);
    k_wscales<<<4, 1024, 0, stream>>>(w1, w2, fw1, fw2, wscales);
    k_pack_weights<<<786, 256, 0, stream>>>(w1, w2, fw1, fw2, wscales, qw1, wpk2, bpk1, qfw2);
    k_conv1_stats<<<25088, 256, 0, stream>>>(x, qw1, b1, stats1);
    k_scales_block<<<1, 64, 0, stream>>>(16, stats1, g1, be1, m1, v1, scales + 0, bn1A, bn1B);
    k_block1<<<12544, 256, 0, stream>>>(x, qw1, b1, scales, bn1A, bn1B, h1q);
    k_conv2s_mfma<<<1568, 256, 0, stream>>>(h1q, wpk2, stats2);
    k_scales2<<<1, 64, 0, stream>>>(stats2, g2, be2, m2, v2, b2, scales, wscales, scales + 3, bn2A, bn2B);
    k_block2_mfma<<<6272, 256, 0, stream>>>(h1q, wpk2, b2, scales, wscales, bn2A, bn2B, h2q);
    k_fc1<<<256, 256, 0, stream>>>(h2q, bpk1, fb1, scales, wscales, fc1o, statsFc);
    k_fc2<<<32, 256, 0, stream>>>(fc1o, qfw2, fb2, statsFc, out, statsOut);
    k_quant_out<<<320, 256, 0, stream>>>(out, statsOut, out_size);
}

// Round 7
// 333.520 us; speedup vs baseline: 2.0939x; 2.0939x over previous
//
#include <hip/hip_runtime.h>
#include <math.h>
#include <limits.h>
#include <stdint.h>

#define QMAXF 127.0f
#define BN_EPS 1e-5f
#define NCOPIES 64

typedef int v4i __attribute__((ext_vector_type(4)));

// ---------- helpers ----------
__device__ __forceinline__ int f2ord(float f){
    int i = __float_as_int(f);
    return i ^ ((i >> 31) & 0x7fffffff);
}
__device__ __forceinline__ float ord2f(int i){
    return __int_as_float(i ^ ((i >> 31) & 0x7fffffff));
}
__device__ __forceinline__ float scale_from_ord(int om){
    return fmaxf(ord2f(om) / QMAXF, 1e-8f);
}
// fake-quant forward: clip(round(x/s))*s  (round = half-to-even, matches jnp.round)
__device__ __forceinline__ float fq_apply(float x, float s){
    float q = rintf(x / s);
    q = fminf(fmaxf(q, -QMAXF), QMAXF);
    return q * s;
}
// return clipped integer level as float
__device__ __forceinline__ float quant_k(float x, float s){
    float q = rintf(x / s);
    return fminf(fmaxf(q, -QMAXF), QMAXF);
}

// ---------- K0: init stat buffers ----------
__global__ void k_init_stats(int* s1, int* s2, int* sf, int* so, int* wsmax){
    int t = blockIdx.x*blockDim.x + threadIdx.x;
    if (t < 2048){ int j = t & 31; s1[t] = (j < 16) ? INT_MAX : INT_MIN; }
    else if (t < 6144){ int u = t - 2048; int j = u & 63; s2[u] = (j < 32) ? INT_MAX : INT_MIN; }
    else if (t < 6272){ int u = t - 6144; sf[u] = ((u & 1) == 0) ? INT_MAX : INT_MIN; }
    else if (t < 6400){ int u = t - 6272; so[u] = ((u & 1) == 0) ? INT_MAX : INT_MIN; }
    else if (t < 6404){ wsmax[t - 6400] = INT_MIN; }
}

// ---------- K1a: per-tensor |w| max (ordered-int atomics; fw1 split over 64 blocks) ----------
__global__ __launch_bounds__(256) void k_wscales(
    const float* __restrict__ w1, const float* __restrict__ w2,
    const float* __restrict__ fw1, const float* __restrict__ fw2,
    int* __restrict__ wsmax)
{
    __shared__ float red[256];
    int t = threadIdx.x, blk = blockIdx.x;
    const float* src; int n, base, which;
    if (blk < 64){ src = fw1; base = blk*3136; n = 3136; which = 2; }
    else if (blk == 64){ src = w1;  base = 0; n = 144;  which = 0; }
    else if (blk == 65){ src = w2;  base = 0; n = 4608; which = 1; }
    else { src = fw2; base = 0; n = 1280; which = 3; }
    float m = 0.f;
    for (int i = t; i < n; i += 256) m = fmaxf(m, fabsf(src[base + i]));
    red[t] = m; __syncthreads();
    for (int off = 128; off; off >>= 1){
        if (t < off) red[t] = fmaxf(red[t], red[t+off]);
        __syncthreads();
    }
    if (t == 0) atomicMax(&wsmax[which], f2ord(red[0]));
}

// ---------- K1b: pack/quantize weights ----------
__global__ __launch_bounds__(256) void k_pack_weights(
    const float* __restrict__ w1, const float* __restrict__ w2,
    const float* __restrict__ fw1, const float* __restrict__ fw2,
    const int* __restrict__ wsmax,
    float* __restrict__ qw1, int8_t* __restrict__ wpk2,
    int8_t* __restrict__ bpk1, float* __restrict__ qfw2,
    float* __restrict__ wscales)
{
    int blk = blockIdx.x, t = threadIdx.x;
    if (blk < 784){
        float s = scale_from_ord(wsmax[2]);
        int i = blk*256 + t;                      // 200704 exact
        int o = i / 1568, k = i - o*1568;
        int c = k / 49, r = k - c*49;
        int kp = r*32 + c;
        int kchunk = kp >> 6, rem = kp & 63, hi = rem >> 4, j = rem & 15;
        int code = (int)quant_k(fw1[i], s);
        bpk1[(o>>4)*25600 + (kchunk*4 + hi)*256 + (o&15)*16 + j] = (int8_t)code;
    } else if (blk == 784){
        float s0 = scale_from_ord(wsmax[0]), s3 = scale_from_ord(wsmax[3]);
        for (int i = t; i < 144; i += 256) qw1[i] = fq_apply(w1[i], s0);
        for (int i = t; i < 1280; i += 256) qfw2[i] = fq_apply(fw2[i], s3);
        for (int i = t; i < 4096; i += 256){
            int o = i >> 5, rem = (i & 31) + 32;  // kp 1568..1599 -> chunk24
            int hi = rem >> 4, j = rem & 15;
            bpk1[(o>>4)*25600 + (24*4 + hi)*256 + (o&15)*16 + j] = 0;
        }
        if (t < 4) wscales[t] = scale_from_ord(wsmax[t]);
    } else {
        float s1 = scale_from_ord(wsmax[1]);
        for (int i = t; i < 6144; i += 256) wpk2[i] = 0;
        __syncthreads();
        for (int i = t; i < 4608; i += 256){
            int co = i / 144, rr = i - co*144, ci = rr / 9, pix = rr - ci*9;
            wpk2[(co >> 4)*3072 + pix*256 + (co & 15)*16 + ci] = (int8_t)(int)quant_k(w2[i], s1);
        }
    }
}

// ---------- K2: conv1 + per-channel min/max (dual order: stream window values into 16 accs) ----------
// block = (pos_block, cg); thread = (b, y, q): 4 consecutive x outputs, 4 channels.
__global__ __launch_bounds__(256) void k_conv1_stats(
    const float* __restrict__ x, const float* __restrict__ qw1, const float* __restrict__ b1,
    int* __restrict__ stats1 /*[64][32]*/)
{
    int t = threadIdx.x;
    int cg = blockIdx.x & 3;
    int pb = blockIdx.x >> 2;           // 0..6271
    float sw[36], sb[4];
    #pragma unroll
    for (int i = 0; i < 36; i++) sw[i] = qw1[cg*36 + i];   // wave-uniform -> SGPR
    #pragma unroll
    for (int c = 0; c < 4; c++) sb[c] = b1[cg*4 + c];
    int tid = pb*256 + t;               // 1,605,632 = 8192*28*7 exact
    int q = tid % 7;
    int rowid = tid / 7;
    int y = rowid % 28;
    int b = rowid / 28;
    const float* xb = x + (size_t)b*784;
    int x0 = 4*q;
    float acc[4][4];                    // [px][c]
    #pragma unroll
    for (int px = 0; px < 4; px++)
        #pragma unroll
        for (int c = 0; c < 4; c++) acc[px][c] = sb[c];
    #pragma unroll
    for (int wy = 0; wy < 3; wy++){
        float v[6];
        int yy = y - 1 + wy;
        if (yy < 0 || yy > 27){
            #pragma unroll
            for (int i2 = 0; i2 < 6; i2++) v[i2] = 0.f;
        } else {
            const float* rp = xb + yy*28;
            float4 f = *(const float4*)(rp + x0);
            v[1] = f.x; v[2] = f.y; v[3] = f.z; v[4] = f.w;
            v[0] = (q > 0) ? rp[x0-1] : 0.f;
            v[5] = (q < 6) ? rp[x0+4] : 0.f;
        }
        #pragma unroll
        for (int wx = 0; wx < 6; wx++){
            float val = v[wx];
            #pragma unroll
            for (int px = 0; px < 4; px++){
                int kx = wx - px;
                if (kx < 0 || kx > 2) continue;
                #pragma unroll
                for (int c = 0; c < 4; c++)
                    acc[px][c] = fmaf(sw[c*9 + wy*3 + kx], val, acc[px][c]);
            }
        }
    }
    float mn[4], mx[4];
    #pragma unroll
    for (int c = 0; c < 4; c++){
        mn[c] = fminf(fminf(acc[0][c], acc[1][c]), fminf(acc[2][c], acc[3][c]));
        mx[c] = fmaxf(fmaxf(acc[0][c], acc[1][c]), fmaxf(acc[2][c], acc[3][c]));
    }
    #pragma unroll
    for (int d = 1; d < 64; d <<= 1){
        #pragma unroll
        for (int c = 0; c < 4; c++){
            mn[c] = fminf(mn[c], __shfl_xor(mn[c], d));
            mx[c] = fmaxf(mx[c], __shfl_xor(mx[c], d));
        }
    }
    if ((t & 63) == 0){
        int* base = stats1 + (blockIdx.x & (NCOPIES-1))*32;
        #pragma unroll
        for (int c = 0; c < 4; c++){
            atomicMin(&base[cg*4 + c],      f2ord(mn[c]));
            atomicMax(&base[16 + cg*4 + c], f2ord(mx[c]));
        }
    }
}

// ---------- scales for block1 ----------
__global__ void k_scales_block(int C, const int* __restrict__ stats,
                               const float* __restrict__ g, const float* __restrict__ be,
                               const float* __restrict__ m, const float* __restrict__ v,
                               float* __restrict__ s_out, float* __restrict__ bnA, float* __restrict__ bnB)
{
    __shared__ float cmn[32], cmx[32];
    int t = threadIdx.x;
    if (t < 2*C){
        bool ismax = t >= C; int c = ismax ? t - C : t;
        int acc = ismax ? INT_MIN : INT_MAX;
        for (int i = 0; i < NCOPIES; i++){
            int u = stats[i*2*C + t];
            acc = ismax ? max(acc, u) : min(acc, u);
        }
        if (ismax) cmx[c] = ord2f(acc); else cmn[c] = ord2f(acc);
    }
    __syncthreads();
    if (t == 0){
        float am = 0.f;
        for (int c = 0; c < C; c++) am = fmaxf(am, fmaxf(fabsf(cmn[c]), fabsf(cmx[c])));
        float sA_ = fmaxf(am / QMAXF, 1e-8f);
        float rmax = 0.f;
        float q1x[32], q1n[32];
        for (int c = 0; c < C; c++){
            q1x[c] = fmaxf(fq_apply(cmx[c], sA_), 0.f);
            q1n[c] = fmaxf(fq_apply(cmn[c], sA_), 0.f);
            rmax = fmaxf(rmax, q1x[c]);
        }
        float sB_ = fmaxf(rmax / QMAXF, 1e-8f);
        float am3 = 0.f;
        for (int c = 0; c < C; c++){
            float inv = g[c] / sqrtf(v[c] + BN_EPS);
            float dd  = be[c] - m[c]*inv;
            bnA[c] = inv; bnB[c] = dd;
            float ha = fmaf(fq_apply(q1x[c], sB_), inv, dd);
            float hb = fmaf(fq_apply(q1n[c], sB_), inv, dd);
            am3 = fmaxf(am3, fmaxf(fabsf(ha), fabsf(hb)));
        }
        float sC_ = fmaxf(am3 / QMAXF, 1e-8f);
        s_out[0] = sA_; s_out[1] = sB_; s_out[2] = sC_;
    }
}

// ---------- K4: fused block1, dual order (32 accs), pool-before-chain (exact) ----------
__global__ __launch_bounds__(256) void k_block1(
    const float* __restrict__ x, const float* __restrict__ qw1, const float* __restrict__ b1,
    const float* __restrict__ scales, const float* __restrict__ bnA, const float* __restrict__ bnB,
    int8_t* __restrict__ h1q)
{
    int t = threadIdx.x;
    int cg = blockIdx.x & 3;
    int pb = blockIdx.x >> 2;            // 0..3135
    float sw[36], sb[4], sA[4], sB[4];
    #pragma unroll
    for (int i = 0; i < 36; i++) sw[i] = qw1[cg*36 + i];
    #pragma unroll
    for (int c = 0; c < 4; c++){
        sb[c] = b1[cg*4 + c]; sA[c] = bnA[cg*4 + c]; sB[c] = bnB[cg*4 + c];
    }
    float s1 = scales[0], s2 = scales[1], s3 = scales[2];
    int tid = pb*256 + t;                // 802,816 = 8192*14*7 exact
    int q = tid % 7;
    int rest = tid / 7;
    int py = rest % 14;
    int b = rest / 14;
    const float* xb = x + (size_t)b*784;
    int x0 = 4*q;
    float acc[2][4][4];                  // [cy][cx][c]
    #pragma unroll
    for (int cy = 0; cy < 2; cy++)
        #pragma unroll
        for (int cx = 0; cx < 4; cx++)
            #pragma unroll
            for (int c = 0; c < 4; c++) acc[cy][cx][c] = sb[c];
    #pragma unroll
    for (int wy = 0; wy < 4; wy++){
        float v[6];
        int yy = 2*py - 1 + wy;
        if (yy < 0 || yy > 27){
            #pragma unroll
            for (int i2 = 0; i2 < 6; i2++) v[i2] = 0.f;
        } else {
            const float* rp = xb + yy*28;
            float4 f = *(const float4*)(rp + x0);
            v[1] = f.x; v[2] = f.y; v[3] = f.z; v[4] = f.w;
            v[0] = (q > 0) ? rp[x0-1] : 0.f;
            v[5] = (q < 6) ? rp[x0+4] : 0.f;
        }
        #pragma unroll
        for (int wx = 0; wx < 6; wx++){
            float val = v[wx];
            #pragma unroll
            for (int cy = 0; cy < 2; cy++){
                int ky = wy - cy;
                if (ky < 0 || ky > 2) continue;
                #pragma unroll
                for (int cx = 0; cx < 4; cx++){
                    int kx = wx - cx;
                    if (kx < 0 || kx > 2) continue;
                    #pragma unroll
                    for (int c = 0; c < 4; c++)
                        acc[cy][cx][c] = fmaf(sw[c*9 + ky*3 + kx], val, acc[cy][cx][c]);
                }
            }
        }
    }
    int p = b*196 + py*14 + 2*q;
    #pragma unroll
    for (int po = 0; po < 2; po++){
        int o4[4];
        #pragma unroll
        for (int c = 0; c < 4; c++){
            float pool = fmaxf(fmaxf(acc[0][2*po][c], acc[0][2*po+1][c]),
                               fmaxf(acc[1][2*po][c], acc[1][2*po+1][c]));
            float h = fq_apply(pool, s1);
            h = fmaxf(h, 0.f);
            h = fq_apply(h, s2);
            h = fmaf(h, sA[c], sB[c]);
            o4[c] = (int)quant_k(h, s3);
        }
        int pk = (o4[0]&255) | ((o4[1]&255)<<8) | ((o4[2]&255)<<16) | ((o4[3]&255)<<24);
        ((int*)h1q)[(p + po)*4 + cg] = pk;
    }
}

// ---------- conv2 MFMA tile ----------
__device__ __forceinline__ void conv2_tile_mfma(
    const int8_t* __restrict__ h1q, const v4i* __restrict__ bv,
    int tile, int l, v4i& acc0, v4i& acc1)
{
    int grow = tile*16 + (l & 15);
    int cell_g = grow >> 2;
    int b = cell_g / 49, cell = cell_g - b*49;
    int sub = grow & 3;
    int qy = cell / 7, qx = cell - qy*7;
    int y = 2*qy + (sub >> 1);
    int x = 2*qx + (sub & 1);
    size_t base = (size_t)b * 196;
    int hi = l >> 4;
    acc0 = (v4i){0,0,0,0};
    acc1 = (v4i){0,0,0,0};
    #pragma unroll
    for (int s = 0; s < 3; s++){
        int tap = 4*s + hi;
        v4i av = {0,0,0,0};
        if (tap < 9){
            int ky = tap / 3, kx = tap - ky*3;
            int yy = y + ky - 1, xc = x + kx - 1;
            if (yy >= 0 && yy < 14 && xc >= 0 && xc < 14)
                av = *(const v4i*)(h1q + (base + yy*14 + xc)*16);
        }
        acc0 = __builtin_amdgcn_mfma_i32_16x16x64_i8(av, bv[s],     acc0, 0, 0, 0);
        acc1 = __builtin_amdgcn_mfma_i32_16x16x64_i8(av, bv[3 + s], acc1, 0, 0, 0);
    }
}

// ---------- K6: conv2 int8 MFMA + per-channel code min/max ----------
__global__ __launch_bounds__(256) void k_conv2s_mfma(
    const int8_t* __restrict__ h1q, const int8_t* __restrict__ wpk2,
    int* __restrict__ stats2)
{
    __shared__ int smn[32], smx[32];
    int t = threadIdx.x, l = t & 63, wid = t >> 6;
    if (t < 32){ smn[t] = INT_MAX; smx[t] = INT_MIN; }
    __syncthreads();
    v4i bv[6];
    #pragma unroll
    for (int nt = 0; nt < 2; nt++)
        #pragma unroll
        for (int s = 0; s < 3; s++)
            bv[nt*3+s] = *(const v4i*)(wpk2 + nt*3072 + (4*s + (l>>4))*256 + (l&15)*16);
    int mn0 = INT_MAX, mx0 = INT_MIN, mn1 = INT_MAX, mx1 = INT_MIN;
    #pragma unroll 1
    for (int it = 0; it < 16; it++){            // 1568 blocks * 16 = 25088 tiles
        int tb = blockIdx.x + it*1568;
        v4i acc0, acc1;
        conv2_tile_mfma(h1q, bv, tb*4 + wid, l, acc0, acc1);
        #pragma unroll
        for (int r = 0; r < 4; r++){
            mn0 = min(mn0, acc0[r]); mx0 = max(mx0, acc0[r]);
            mn1 = min(mn1, acc1[r]); mx1 = max(mx1, acc1[r]);
        }
    }
    mn0 = min(mn0, __shfl_xor(mn0, 16)); mn0 = min(mn0, __shfl_xor(mn0, 32));
    mx0 = max(mx0, __shfl_xor(mx0, 16)); mx0 = max(mx0, __shfl_xor(mx0, 32));
    mn1 = min(mn1, __shfl_xor(mn1, 16)); mn1 = min(mn1, __shfl_xor(mn1, 32));
    mx1 = max(mx1, __shfl_xor(mx1, 16)); mx1 = max(mx1, __shfl_xor(mx1, 32));
    if (l < 16){
        atomicMin(&smn[l], mn0);      atomicMax(&smx[l], mx0);
        atomicMin(&smn[16 + l], mn1); atomicMax(&smx[16 + l], mx1);
    }
    __syncthreads();
    if (t < 32){
        int* base = stats2 + (blockIdx.x & (NCOPIES-1))*64;
        atomicMin(&base[t],      smn[t]);
        atomicMax(&base[t + 32], smx[t]);
    }
}

// ---------- scales for block2 from int code stats ----------
__global__ void k_scales2(const int* __restrict__ stats,
                          const float* __restrict__ g, const float* __restrict__ be,
                          const float* __restrict__ m, const float* __restrict__ v,
                          const float* __restrict__ b2,
                          const float* __restrict__ scales, const float* __restrict__ wscales,
                          float* __restrict__ s_out, float* __restrict__ bnA, float* __restrict__ bnB)
{
    __shared__ float cmn[32], cmx[32];
    int t = threadIdx.x;
    float S = scales[2] * wscales[1];
    if (t < 64){
        bool ismax = t >= 32; int c = t & 31;
        int acc = ismax ? INT_MIN : INT_MAX;
        for (int i = 0; i < NCOPIES; i++){
            int u = stats[i*64 + t];
            acc = ismax ? max(acc, u) : min(acc, u);
        }
        float val = fmaf(S, (float)acc, b2[c]);
        if (ismax) cmx[c] = val; else cmn[c] = val;
    }
    __syncthreads();
    if (t == 0){
        float am = 0.f;
        for (int c = 0; c < 32; c++) am = fmaxf(am, fmaxf(fabsf(cmn[c]), fabsf(cmx[c])));
        float sA_ = fmaxf(am / QMAXF, 1e-8f);
        float rmax = 0.f;
        float q1x[32], q1n[32];
        for (int c = 0; c < 32; c++){
            q1x[c] = fmaxf(fq_apply(cmx[c], sA_), 0.f);
            q1n[c] = fmaxf(fq_apply(cmn[c], sA_), 0.f);
            rmax = fmaxf(rmax, q1x[c]);
        }
        float sB_ = fmaxf(rmax / QMAXF, 1e-8f);
        float am3 = 0.f;
        for (int c = 0; c < 32; c++){
            float inv = g[c] / sqrtf(v[c] + BN_EPS);
            float dd  = be[c] - m[c]*inv;
            bnA[c] = inv; bnB[c] = dd;
            float ha = fmaf(fq_apply(q1x[c], sB_), inv, dd);
            float hb = fmaf(fq_apply(q1n[c], sB_), inv, dd);
            am3 = fmaxf(am3, fmaxf(fabsf(ha), fabsf(hb)));
        }
        float sC_ = fmaxf(am3 / QMAXF, 1e-8f);
        s_out[0] = sA_; s_out[1] = sB_; s_out[2] = sC_;
    }
}

// ---------- K8: conv2 MFMA -> pool -> chain -> h2q codes (4 tiles/wave) ----------
__global__ __launch_bounds__(256) void k_block2_mfma(
    const int8_t* __restrict__ h1q, const int8_t* __restrict__ wpk2,
    const float* __restrict__ b2, const float* __restrict__ scales,
    const float* __restrict__ wscales,
    const float* __restrict__ bnA, const float* __restrict__ bnB,
    int8_t* __restrict__ h2q)
{
    __shared__ float sb[32], sA[32], sB[32];
    __shared__ int pbufi[512];
    char* pbuf = (char*)pbufi;
    int t = threadIdx.x, l = t & 63, wid = t >> 6;
    if (t < 32){ sb[t] = b2[t]; sA[t] = bnA[t]; sB[t] = bnB[t]; }
    __syncthreads();
    float S = scales[2] * wscales[1];
    float s4 = scales[3], s5 = scales[4], s6 = scales[5];
    v4i bv[6];
    #pragma unroll
    for (int nt = 0; nt < 2; nt++)
        #pragma unroll
        for (int s = 0; s < 3; s++)
            bv[nt*3+s] = *(const v4i*)(wpk2 + nt*3072 + (4*s + (l>>4))*256 + (l&15)*16);
    #pragma unroll 1
    for (int it = 0; it < 4; it++){
        int tile = blockIdx.x*16 + wid*4 + it;   // grid 6272: tiles 0..100351
        v4i acc0, acc1;
        conv2_tile_mfma(h1q, bv, tile, l, acc0, acc1);
        int cell_local = wid*16 + it*4 + (l >> 4);
        #pragma unroll
        for (int nt = 0; nt < 2; nt++){
            v4i a = nt ? acc1 : acc0;
            int pool = max(max(a[0], a[1]), max(a[2], a[3]));
            int co = nt*16 + (l & 15);
            float conv = fmaf(S, (float)pool, sb[co]);
            float h = fq_apply(conv, s4);
            h = fmaxf(h, 0.f);
            h = fq_apply(h, s5);
            h = fmaf(h, sA[co], sB[co]);
            pbuf[cell_local*32 + co] = (char)(int)quant_k(h, s6);
        }
    }
    __syncthreads();
    #pragma unroll
    for (int i = t; i < 512; i += 256)
        ((int*)h2q)[blockIdx.x*512 + i] = pbufi[i];
}

// ---------- K9: fc1 int8 MFMA: M=8192, N=128, K=1600 (padded) ----------
__global__ __launch_bounds__(256) void k_fc1(
    const int8_t* __restrict__ h2q, const int8_t* __restrict__ bpk1,
    const float* __restrict__ fb1, const float* __restrict__ scales,
    const float* __restrict__ wscales,
    float* __restrict__ fc1o, int* __restrict__ statsFc)
{
    __shared__ int smn, smx;
    int t = threadIdx.x, l = t & 63, wid = t >> 6;
    if (t == 0){ smn = INT_MAX; smx = INT_MIN; }
    __syncthreads();
    int wave_id = blockIdx.x*4 + wid;     // 1024 waves
    int mtile = wave_id >> 1;             // 0..511
    int half = wave_id & 1;
    int hi = l >> 4, lo = l & 15;
    const int8_t* arow = h2q + (size_t)(mtile*16 + lo)*1568;
    v4i acc[4];
    #pragma unroll
    for (int g = 0; g < 4; g++) acc[g] = (v4i){0,0,0,0};
    #pragma unroll 1
    for (int kc = 0; kc < 25; kc++){
        int koff = kc*64 + hi*16;
        v4i av = (v4i){0,0,0,0};
        if (koff < 1568) av = *(const v4i*)(arow + koff);
        #pragma unroll
        for (int g = 0; g < 4; g++){
            v4i bvv = *(const v4i*)(bpk1 + (half*4 + g)*25600 + (kc*4 + hi)*256 + lo*16);
            acc[g] = __builtin_amdgcn_mfma_i32_16x16x64_i8(av, bvv, acc[g], 0, 0, 0);
        }
    }
    float Sfc = scales[5] * wscales[2];
    float lmn = INFINITY, lmx = -INFINITY;
    #pragma unroll
    for (int g = 0; g < 4; g++){
        int o = (half*4 + g)*16 + lo;
        float bias = fb1[o];
        #pragma unroll
        for (int r = 0; r < 4; r++){
            int m = mtile*16 + hi*4 + r;
            float val = fmaf(Sfc, (float)acc[g][r], bias);
            fc1o[(size_t)m*128 + o] = val;
            lmn = fminf(lmn, val); lmx = fmaxf(lmx, val);
        }
    }
    #pragma unroll
    for (int d = 1; d < 64; d <<= 1){
        lmn = fminf(lmn, __shfl_xor(lmn, d));
        lmx = fmaxf(lmx, __shfl_xor(lmx, d));
    }
    if (l == 0){
        atomicMin(&smn, f2ord(lmn));
        atomicMax(&smx, f2ord(lmx));
    }
    __syncthreads();
    if (t == 0){
        int* base = statsFc + (blockIdx.x & (NCOPIES-1))*2;
        atomicMin(&base[0], smn); atomicMax(&base[1], smx);
    }
}

// ---------- K12: fc2 with inline h3 quantization (s7/s8 derived in prologue) ----------
__global__ __launch_bounds__(256) void k_fc2(
    const float* __restrict__ fc1o, const float* __restrict__ qfw2, const float* __restrict__ fb2,
    const int* __restrict__ statsFc, float* __restrict__ out, int* __restrict__ statsOut)
{
    __shared__ float sw[1280], sb2[10];
    __shared__ float s7s, s8s;
    __shared__ int smn, smx;
    int t = threadIdx.x;
    for (int i = t; i < 1280; i += 256) sw[i] = qfw2[i];
    if (t < 10) sb2[t] = fb2[t];
    if (t == 0){
        smn = INT_MAX; smx = INT_MIN;
        int mni = INT_MAX, mxi = INT_MIN;
        for (int i = 0; i < NCOPIES; i++){ mni = min(mni, statsFc[i*2]); mxi = max(mxi, statsFc[i*2+1]); }
        float mn = ord2f(mni), mx = ord2f(mxi);
        float am = fmaxf(fabsf(mn), fabsf(mx));
        float s7 = fmaxf(am / QMAXF, 1e-8f);
        float rmx = fmaxf(fq_apply(mx, s7), 0.f);
        s7s = s7; s8s = fmaxf(rmx / QMAXF, 1e-8f);
    }
    __syncthreads();
    float s7 = s7s, s8 = s8s;
    int b = blockIdx.x*256 + t;   // 8192 exact (32 blocks)
    float acc[10];
    #pragma unroll
    for (int j = 0; j < 10; j++) acc[j] = sb2[j];
    const float* fp = fc1o + (size_t)b*128;
    for (int k = 0; k < 128; k += 4){
        float4 f = *(const float4*)(fp + k);
        float v0 = s8 * quant_k(fmaxf(fq_apply(f.x, s7), 0.f), s8);
        float v1 = s8 * quant_k(fmaxf(fq_apply(f.y, s7), 0.f), s8);
        float v2 = s8 * quant_k(fmaxf(fq_apply(f.z, s7), 0.f), s8);
        float v3 = s8 * quant_k(fmaxf(fq_apply(f.w, s7), 0.f), s8);
        #pragma unroll
        for (int j = 0; j < 10; j++){
            float a = acc[j];
            a = fmaf(v0, sw[j*128 + k],     a);
            a = fmaf(v1, sw[j*128 + k + 1], a);
            a = fmaf(v2, sw[j*128 + k + 2], a);
            a = fmaf(v3, sw[j*128 + k + 3], a);
            acc[j] = a;
        }
    }
    float lmn = INFINITY, lmx = -INFINITY;
    #pragma unroll
    for (int j = 0; j < 10; j++){
        out[(size_t)b*10 + j] = acc[j];
        lmn = fminf(lmn, acc[j]); lmx = fmaxf(lmx, acc[j]);
    }
    atomicMin(&smn, f2ord(lmn)); atomicMax(&smx, f2ord(lmx));
    __syncthreads();
    if (t == 0){
        int* base = statsOut + (blockIdx.x & (NCOPIES-1))*2;
        atomicMin(&base[0], smn); atomicMax(&base[1], smx);
    }
}

// ---------- K14: final fake-quant of d_out (s9 derived in prologue) ----------
__global__ void k_quant_out(float* __restrict__ out, const int* __restrict__ statsOut, int n){
    __shared__ float s9s;
    if (threadIdx.x == 0){
        int mni = INT_MAX, mxi = INT_MIN;
        for (int i = 0; i < NCOPIES; i++){ mni = min(mni, statsOut[i*2]); mxi = max(mxi, statsOut[i*2+1]); }
        float am = fmaxf(fabsf(ord2f(mni)), fabsf(ord2f(mxi)));
        s9s = fmaxf(am / QMAXF, 1e-8f);
    }
    __syncthreads();
    int i = blockIdx.x*256 + threadIdx.x;
    if (i < n) out[i] = fq_apply(out[i], s9s);
}

// =================== host ===================
extern "C" void kernel_launch(void* const* d_in, const int* in_sizes, int n_in,
                              void* d_out, int out_size, void* d_ws, size_t ws_size,
                              hipStream_t stream)
{
    const float* x   = (const float*)d_in[0];
    const float* w1  = (const float*)d_in[1];
    const float* b1  = (const float*)d_in[2];
    const float* g1  = (const float*)d_in[3];
    const float* be1 = (const float*)d_in[4];
    const float* m1  = (const float*)d_in[5];
    const float* v1  = (const float*)d_in[6];
    const float* w2  = (const float*)d_in[7];
    const float* b2  = (const float*)d_in[8];
    const float* g2  = (const float*)d_in[9];
    const float* be2 = (const float*)d_in[10];
    const float* m2  = (const float*)d_in[11];
    const float* v2  = (const float*)d_in[12];
    const float* fw1 = (const float*)d_in[13];
    const float* fb1 = (const float*)d_in[14];
    const float* fw2 = (const float*)d_in[15];
    const float* fb2 = (const float*)d_in[16];
    float* out = (float*)d_out;

    char* ws = (char*)d_ws;
    size_t off = 0;
    auto alloc = [&](size_t bytes)->char*{
        char* p = ws + off;
        off = (off + bytes + 255) & ~(size_t)255;
        return p;
    };
    float* qw1    = (float*)alloc(144*4);
    int8_t* wpk2  = (int8_t*)alloc(6144);
    int8_t* bpk1  = (int8_t*)alloc(204800);
    float* qfw2   = (float*)alloc(1280*4);
    float* scales = (float*)alloc(16*4);
    float* wscales= (float*)alloc(4*4);
    int* wsmax    = (int*)alloc(4*4);
    float* bn1A   = (float*)alloc(16*4);
    float* bn1B   = (float*)alloc(16*4);
    float* bn2A   = (float*)alloc(32*4);
    float* bn2B   = (float*)alloc(32*4);
    int* stats1   = (int*)alloc(64*32*4);
    int* stats2   = (int*)alloc(64*64*4);
    int* statsFc  = (int*)alloc(64*2*4);
    int* statsOut = (int*)alloc(64*2*4);
    int8_t* h1q   = (int8_t*)alloc((size_t)8192*196*16);
    int8_t* h2q   = (int8_t*)alloc((size_t)8192*49*32);
    float* fc1o   = (float*)alloc((size_t)8192*128*4);
    (void)ws_size;

    k_init_stats<<<26, 256, 0, stream>>>(stats1, stats2, statsFc, statsOut, wsmax);
    k_wscales<<<67, 256, 0, stream>>>(w1, w2, fw1, fw2, wsmax);
    k_pack_weights<<<786, 256, 0, stream>>>(w1, w2, fw1, fw2, wsmax, qw1, wpk2, bpk1, qfw2, wscales);
    k_conv1_stats<<<25088, 256, 0, stream>>>(x, qw1, b1, stats1);
    k_scales_block<<<1, 64, 0, stream>>>(16, stats1, g1, be1, m1, v1, scales + 0, bn1A, bn1B);
    k_block1<<<12544, 256, 0, stream>>>(x, qw1, b1, scales, bn1A, bn1B, h1q);
    k_conv2s_mfma<<<1568, 256, 0, stream>>>(h1q, wpk2, stats2);
    k_scales2<<<1, 64, 0, stream>>>(stats2, g2, be2, m2, v2, b2, scales, wscales, scales + 3, bn2A, bn2B);
    k_block2_mfma<<<6272, 256, 0, stream>>>(h1q, wpk2, b2, scales, wscales, bn2A, bn2B, h2q);
    k_fc1<<<256, 256, 0, stream>>>(h2q, bpk1, fb1, scales, wscales, fc1o, statsFc);
    k_fc2<<<32, 256, 0, stream>>>(fc1o, qfw2, fb2, statsFc, out, statsOut);
    k_quant_out<<<320, 256, 0, stream>>>(out, statsOut, out_size);
}